// Round 2
// baseline (672.161 us; speedup 1.0000x reference)
//
#include <hip/hip_runtime.h>
#include <hip/hip_bf16.h>

#define BTT 48      // B*T
#define SEQ 512     // spatial tokens (attention length)
#define DIM 256     // model dim
#define NH  8       // heads
#define HD  32      // head dim

typedef unsigned short u16;

__device__ __forceinline__ float b2f(u16 u) {
  union { unsigned int i; float f; } x; x.i = ((unsigned int)u) << 16; return x.f;
}
__device__ __forceinline__ u16 f2b(float f) {
  __hip_bfloat16 h = __float2bfloat16(f);   // RTNE
  union { __hip_bfloat16 h; u16 u; } c; c.h = h; return c.u;
}
// 8 bf16 (16B) -> 8 fp32, single b128 load
__device__ __forceinline__ void unpack8(const u16* p, float* f) {
  union { uint4 v; unsigned int w[4]; } u;
  u.v = *reinterpret_cast<const uint4*>(p);
#pragma unroll
  for (int g = 0; g < 4; ++g) {
    union { unsigned int i; float f; } lo, hi;
    lo.i = u.w[g] << 16;
    hi.i = u.w[g] & 0xffff0000u;
    f[2 * g]     = lo.f;
    f[2 * g + 1] = hi.f;
  }
}

// fp32 -> bf16 conversion, 4 elems/thread
__global__ __launch_bounds__(256) void cvt_kernel(const float* __restrict__ src,
                                                  u16* __restrict__ dst, int n) {
  int i = (blockIdx.x * 256 + threadIdx.x) * 4;
  if (i >= n) return;
  float4 v = *reinterpret_cast<const float4*>(src + i);
  union { uint2 w; u16 u[4]; } o;
  o.u[0] = f2b(v.x); o.u[1] = f2b(v.y); o.u[2] = f2b(v.z); o.u[3] = f2b(v.w);
  *reinterpret_cast<uint2*>(dst + i) = o.w;
}

// C[M,N] = A[M,K] @ B[K,N], bf16 in, OUT out (u16 bf16 or float), fp32 accum.
// 128x128 tile, BK=32, 256 threads, 8x8 per thread, k-major LDS.
template <typename OUT>
__global__ __launch_bounds__(256) void gemm128(const u16* __restrict__ A,
                                               const u16* __restrict__ B,
                                               OUT* __restrict__ C,
                                               int M, int N, int K) {
  __shared__ u16 As[32][128];   // k-major: As[kk][m]
  __shared__ u16 Bs[32][128];   // k-major: Bs[kk][n]
  const int t  = threadIdx.x;
  const int tx = t & 15, ty = t >> 4;
  const int bm = blockIdx.x * 128;
  const int bn = blockIdx.y * 128;

  float acc[8][8];
#pragma unroll
  for (int i = 0; i < 8; ++i)
#pragma unroll
    for (int j = 0; j < 8; ++j) acc[i][j] = 0.f;

  const int ar  = t >> 2, ac8 = (t & 3) * 8;   // A: 64 rows x 32k per iter
  const int bkr = t >> 3, bc8 = (t & 7) * 8;   // B: 32 rows x 64n per iter

  for (int k0 = 0; k0 < K; k0 += 32) {
    // A tile: load 8 contiguous k, scatter k-major (transpose in LDS)
#pragma unroll
    for (int it = 0; it < 2; ++it) {
      int r = ar + it * 64;
      union { uint4 v; u16 u[8]; } a;
      a.v = *reinterpret_cast<const uint4*>(A + (size_t)(bm + r) * K + k0 + ac8);
#pragma unroll
      for (int e = 0; e < 8; ++e) As[ac8 + e][r] = a.u[e];
    }
    // B tile: already k-major in global, straight b128 copy
#pragma unroll
    for (int it = 0; it < 2; ++it) {
      int c = bc8 + it * 64;
      *reinterpret_cast<uint4*>(&Bs[bkr][c]) =
          *reinterpret_cast<const uint4*>(B + (size_t)(k0 + bkr) * N + bn + c);
    }
    __syncthreads();
#pragma unroll 8
    for (int kk = 0; kk < 32; ++kk) {
      float a[8], b[8];
      unpack8(&As[kk][ty * 8], a);
      unpack8(&Bs[kk][tx * 8], b);
#pragma unroll
      for (int i = 0; i < 8; ++i)
#pragma unroll
        for (int j = 0; j < 8; ++j)
          acc[i][j] = fmaf(a[i], b[j], acc[i][j]);
    }
    __syncthreads();
  }
#pragma unroll
  for (int i = 0; i < 8; ++i) {
    if constexpr (sizeof(OUT) == 2) {
      union { uint4 v; u16 u[8]; } o;
#pragma unroll
      for (int j = 0; j < 8; ++j) o.u[j] = f2b(acc[i][j]);
      *reinterpret_cast<uint4*>((u16*)C + (size_t)(bm + ty * 8 + i) * N + bn + tx * 8) = o.v;
    } else {
      float* Cf = (float*)C + (size_t)(bm + ty * 8 + i) * N + bn + tx * 8;
      float4 lo = make_float4(acc[i][0], acc[i][1], acc[i][2], acc[i][3]);
      float4 hi = make_float4(acc[i][4], acc[i][5], acc[i][6], acc[i][7]);
      *reinterpret_cast<float4*>(Cf)     = lo;
      *reinterpret_cast<float4*>(Cf + 4) = hi;
    }
  }
}

// One block per (q-half, head, bt). 256 threads; thread = one q row.
// K,V [512][32] bf16 staged in LDS (64 KiB). Online softmax, fp32 state.
__global__ __launch_bounds__(256) void attn_kernel(const u16* __restrict__ Q,
                                                   const u16* __restrict__ Kin,
                                                   const u16* __restrict__ Vin,
                                                   const float* __restrict__ sim,
                                                   u16* __restrict__ O) {
  __shared__ u16 Ks[SEQ * HD];
  __shared__ u16 Vs[SEQ * HD];
  const int t  = threadIdx.x;
  const int qt = blockIdx.x;   // 0..1
  const int h  = blockIdx.y;   // 0..7
  const int bt = blockIdx.z;   // 0..47
  const size_t base = (size_t)bt * SEQ * DIM + (size_t)h * HD;

  const int lr = t >> 2, lc8 = (t & 3) * 8;
#pragma unroll
  for (int it = 0; it < 8; ++it) {
    int row = it * 64 + lr;
    *reinterpret_cast<uint4*>(&Ks[row * HD + lc8]) =
        *reinterpret_cast<const uint4*>(Kin + base + (size_t)row * DIM + lc8);
    *reinterpret_cast<uint4*>(&Vs[row * HD + lc8]) =
        *reinterpret_cast<const uint4*>(Vin + base + (size_t)row * DIM + lc8);
  }
  __syncthreads();

  const int qrow = qt * 256 + t;
  float q[HD];
#pragma unroll
  for (int g = 0; g < 4; ++g) unpack8(Q + base + (size_t)qrow * DIM + g * 8, &q[g * 8]);

  const float* simrow = sim + (size_t)qrow * SEQ;
  const float scale = 0.17677669529663687f;  // 1/sqrt(32)

  float mx = -1e30f, sum = 0.f;
  float acc[HD];
#pragma unroll
  for (int j = 0; j < HD; ++j) acc[j] = 0.f;

  for (int m = 0; m < SEQ; ++m) {
    float s = 0.f;
#pragma unroll
    for (int g = 0; g < 4; ++g) {
      float kb[8];
      unpack8(&Ks[m * HD + g * 8], kb);
#pragma unroll
      for (int e = 0; e < 8; ++e) s = fmaf(q[g * 8 + e], kb[e], s);
    }
    s = fmaf(s, scale, simrow[m]);
    if (s > mx) {                       // rare (~ln(512) times): rescale state
      float c = __expf(mx - s);
      sum *= c;
#pragma unroll
      for (int j = 0; j < HD; ++j) acc[j] *= c;
      mx = s;
    }
    float p = __expf(s - mx);
    sum += p;
#pragma unroll
    for (int g = 0; g < 4; ++g) {
      float vb[8];
      unpack8(&Vs[m * HD + g * 8], vb);
#pragma unroll
      for (int e = 0; e < 8; ++e) acc[g * 8 + e] = fmaf(p, vb[e], acc[g * 8 + e]);
    }
  }
  const float inv = 1.f / sum;
#pragma unroll
  for (int g = 0; g < 4; ++g) {
    union { uint4 v; u16 u[8]; } o;
#pragma unroll
    for (int e = 0; e < 8; ++e) o.u[e] = f2b(acc[g * 8 + e] * inv);
    *reinterpret_cast<uint4*>(O + base + (size_t)qrow * DIM + g * 8) = o.v;
  }
}

extern "C" void kernel_launch(void* const* d_in, const int* in_sizes, int n_in,
                              void* d_out, int out_size, void* d_ws, size_t ws_size,
                              hipStream_t stream) {
  const float* x   = (const float*)d_in[0];
  const float* sim = (const float*)d_in[1];
  const float* Wq  = (const float*)d_in[2];
  const float* Wk  = (const float*)d_in[3];
  const float* Wv  = (const float*)d_in[4];
  const float* Wo  = (const float*)d_in[5];
  float* out = (float*)d_out;

  const int M = BTT * SEQ;               // 24576
  const size_t sz = (size_t)M * DIM;     // elements per [M,DIM] buffer
  const int WN = DIM * DIM;              // 65536

  u16* Qw  = (u16*)d_ws;                 // [M,DIM] bf16
  u16* Kw  = Qw + sz;
  u16* Vw  = Kw + sz;
  u16* Xb  = Vw + sz;                    // bf16 x; reused as Aw after attn
  u16* Wqb = Xb + sz;
  u16* Wkb = Wqb + WN;
  u16* Wvb = Wkb + WN;
  u16* Wob = Wvb + WN;

  // fp32 -> bf16 conversions
  cvt_kernel<<<(int)(sz / 4 / 256), 256, 0, stream>>>(x, Xb, (int)sz);
  cvt_kernel<<<WN / 4 / 256, 256, 0, stream>>>(Wq, Wqb, WN);
  cvt_kernel<<<WN / 4 / 256, 256, 0, stream>>>(Wk, Wkb, WN);
  cvt_kernel<<<WN / 4 / 256, 256, 0, stream>>>(Wv, Wvb, WN);
  cvt_kernel<<<WN / 4 / 256, 256, 0, stream>>>(Wo, Wob, WN);

  dim3 gg(M / 128, DIM / 128);           // (192, 2)
  gemm128<u16><<<gg, 256, 0, stream>>>(Xb, Wqb, Qw, M, DIM, DIM);
  gemm128<u16><<<gg, 256, 0, stream>>>(Xb, Wkb, Kw, M, DIM, DIM);
  gemm128<u16><<<gg, 256, 0, stream>>>(Xb, Wvb, Vw, M, DIM, DIM);
  u16* Aw = Xb;                          // x dead after V-GEMM; reuse buffer
  attn_kernel<<<dim3(2, NH, BTT), 256, 0, stream>>>(Qw, Kw, Vw, sim, Aw);
  gemm128<float><<<gg, 256, 0, stream>>>(Aw, Wob, out, M, DIM, DIM);
}

// Round 3
// 184.424 us; speedup vs baseline: 3.6447x; 3.6447x over previous
//
#include <hip/hip_runtime.h>
#include <hip/hip_bf16.h>

#define BTT 48      // B*T
#define SEQ 512     // spatial tokens
#define DIM 256     // model dim
#define NH  8       // heads
#define HD  32      // head dim

typedef unsigned short u16;
typedef __attribute__((ext_vector_type(8))) short bf16x8;
typedef __attribute__((ext_vector_type(4))) float f32x4;

__device__ __forceinline__ u16 f2b(float f) {
  __hip_bfloat16 h = __float2bfloat16(f);
  union { __hip_bfloat16 h; u16 u; } c; c.h = h; return c.u;
}
__device__ __forceinline__ bf16x8 ldfrag8(const u16* p) {   // LDS, 8B-aligned
  union { uint2 u[2]; bf16x8 v; } f;
  f.u[0] = *reinterpret_cast<const uint2*>(p);
  f.u[1] = *reinterpret_cast<const uint2*>(p + 4);
  return f.v;
}
__device__ __forceinline__ bf16x8 ldfrag_g(const u16* p) {  // global, 16B-aligned
  union { uint4 u; bf16x8 v; } f;
  f.u = *reinterpret_cast<const uint4*>(p);
  return f.v;
}

// ---- fp32 -> bf16 flat conversion (x) ----
__global__ __launch_bounds__(256) void cvt_kernel(const float* __restrict__ src,
                                                  u16* __restrict__ dst, int n) {
  int i = (blockIdx.x * 256 + threadIdx.x) * 4;
  if (i >= n) return;
  float4 v = *reinterpret_cast<const float4*>(src + i);
  union { uint2 w; u16 u[4]; } o;
  o.u[0] = f2b(v.x); o.u[1] = f2b(v.y); o.u[2] = f2b(v.z); o.u[3] = f2b(v.w);
  *reinterpret_cast<uint2*>(dst + i) = o.w;
}

// ---- weight cvt + transpose: W[256][256] fp32 (k,n) -> Bt[256][256] bf16 (n,k) ----
__global__ __launch_bounds__(256) void wtcvt_kernel(const float* __restrict__ W,
                                                    u16* __restrict__ Bt) {
  __shared__ float Ls[64][65];
  const int t = threadIdx.x;
  const int kt = blockIdx.x * 64, nt = blockIdx.y * 64;
#pragma unroll
  for (int it = 0; it < 4; ++it) {
    int r = (t >> 4) + it * 16;          // k local
    int c = (t & 15) * 4;                // n local
    float4 v = *reinterpret_cast<const float4*>(&W[(size_t)(kt + r) * 256 + nt + c]);
    Ls[r][c] = v.x; Ls[r][c + 1] = v.y; Ls[r][c + 2] = v.z; Ls[r][c + 3] = v.w;
  }
  __syncthreads();
  const int n = t >> 2, kc = (t & 3) * 16;
  union { uint4 u[2]; u16 s[16]; } ob;
#pragma unroll
  for (int j = 0; j < 16; ++j) ob.s[j] = f2b(Ls[kc + j][n]);
  u16* dst = Bt + (size_t)(nt + n) * 256 + kt + kc;
  *reinterpret_cast<uint4*>(dst)     = ob.u[0];
  *reinterpret_cast<uint4*>(dst + 8) = ob.u[1];
}

// ---- sim[q][k] fp32 -> simT2[k>>2][q][k&3] fp32 (bias packed for S^T C/D layout) ----
__global__ __launch_bounds__(256) void simpack_kernel(const float* __restrict__ sim,
                                                      float* __restrict__ simT2) {
  int gid = blockIdx.x * 256 + threadIdx.x;   // 0..65535
  int q = gid & 511, k4 = gid >> 9;
  float4 v = *reinterpret_cast<const float4*>(&sim[(size_t)q * 512 + k4 * 4]);
  *reinterpret_cast<float4*>(&simT2[((size_t)k4 * 512 + q) * 4]) = v;
}

// ---- MFMA GEMM: C[M,N] = A[M,K] * B[K,N], Bt = B^T [N][K]; bf16 in, OUT out ----
template <typename OUT>
__global__ __launch_bounds__(256) void gemm_mfma(const u16* __restrict__ A,
                                                 const u16* __restrict__ Bt,
                                                 OUT* __restrict__ C,
                                                 int M, int N, int K) {
  __shared__ u16 As[128][36];   // [m][k] pad 36 (72B rows: b64-aligned, 16 banks)
  __shared__ u16 Bs[128][36];   // [n][k]
  const int t = threadIdx.x, lane = t & 63, w = t >> 6;
  const int g = lane >> 4, ln = lane & 15;
  const int bm = blockIdx.x * 128, bn = blockIdx.y * 128;
  const int wr = (w & 1) * 64, wc = (w >> 1) * 64;
  const f32x4 zf = {0.f, 0.f, 0.f, 0.f};
  f32x4 acc[4][4];
#pragma unroll
  for (int i = 0; i < 4; ++i)
#pragma unroll
    for (int j = 0; j < 4; ++j) acc[i][j] = zf;

  for (int k0 = 0; k0 < K; k0 += 32) {
    const int c8 = (t & 3) * 8;
#pragma unroll
    for (int p = 0; p < 2; ++p) {
      const int r = (t >> 2) + p * 64;
      union { uint4 u4; uint2 u2[2]; } av, bv;
      av.u4 = *reinterpret_cast<const uint4*>(&A[(size_t)(bm + r) * K + k0 + c8]);
      bv.u4 = *reinterpret_cast<const uint4*>(&Bt[(size_t)(bn + r) * K + k0 + c8]);
      *reinterpret_cast<uint2*>(&As[r][c8])     = av.u2[0];
      *reinterpret_cast<uint2*>(&As[r][c8 + 4]) = av.u2[1];
      *reinterpret_cast<uint2*>(&Bs[r][c8])     = bv.u2[0];
      *reinterpret_cast<uint2*>(&Bs[r][c8 + 4]) = bv.u2[1];
    }
    __syncthreads();
    bf16x8 af[4], bfr[4];
#pragma unroll
    for (int i = 0; i < 4; ++i) af[i]  = ldfrag8(&As[wr + i * 16 + ln][g * 8]);
#pragma unroll
    for (int j = 0; j < 4; ++j) bfr[j] = ldfrag8(&Bs[wc + j * 16 + ln][g * 8]);
#pragma unroll
    for (int i = 0; i < 4; ++i)
#pragma unroll
      for (int j = 0; j < 4; ++j)
        acc[i][j] = __builtin_amdgcn_mfma_f32_16x16x32_bf16(af[i], bfr[j], acc[i][j], 0, 0, 0);
    __syncthreads();
  }
#pragma unroll
  for (int i = 0; i < 4; ++i)
#pragma unroll
    for (int j = 0; j < 4; ++j)
#pragma unroll
      for (int r = 0; r < 4; ++r) {
        const int row = bm + wr + i * 16 + g * 4 + r;
        const int col = bn + wc + j * 16 + ln;
        if constexpr (sizeof(OUT) == 2)
          ((u16*)C)[(size_t)row * N + col] = f2b(acc[i][j][r]);
        else
          ((float*)C)[(size_t)row * N + col] = acc[i][j][r];
      }
}

// ---- MFMA flash attention, swapped QK^T (S^T = K*Q^T so col = q-row) ----
// Block: 256 threads = 4 waves, 256 q-rows (64/wave). K/V streamed KBLK=64.
__global__ __launch_bounds__(256) void attn_mfma(const u16* __restrict__ Q,
                                                 const u16* __restrict__ Kin,
                                                 const u16* __restrict__ Vin,
                                                 const float* __restrict__ simT2,
                                                 u16* __restrict__ O) {
  __shared__ u16 Ks[64][36];        // [kv][hd]
  __shared__ u16 Vt[32][68];        // [hd][kv]
  __shared__ u16 Pws[4][64][68];    // per-wave P [qrow][kv]

  const int t = threadIdx.x;
  const int lane = t & 63, w = t >> 6;
  const int g = lane >> 4, ln = lane & 15;
  const int qb = blockIdx.x * 256;
  const int h = blockIdx.y, bt = blockIdx.z;
  const size_t base = (size_t)bt * SEQ * DIM + (size_t)h * HD;
  const int wq = qb + w * 64;       // wave's first q-row
  const float scale = 0.17677669529663687f;  // 1/sqrt(32)
  const f32x4 zf = {0.f, 0.f, 0.f, 0.f};

  // Q fragments (B-operand): lane: qrow = wq+qt*16+ln, hd = g*8..+7
  bf16x8 qf[4];
#pragma unroll
  for (int qt = 0; qt < 4; ++qt)
    qf[qt] = ldfrag_g(&Q[base + (size_t)(wq + qt * 16 + ln) * DIM + g * 8]);

  f32x4 o[4][2];
  float m[4], l[4];
#pragma unroll
  for (int qt = 0; qt < 4; ++qt) {
    o[qt][0] = zf; o[qt][1] = zf; m[qt] = -1e30f; l[qt] = 0.f;
  }

  for (int it = 0; it < 8; ++it) {
    const int k0 = it * 64;
    {   // stage K (row-major) and V (transposed) tiles
      const int r = t >> 2, c8 = (t & 3) * 8;
      union { uint4 u4; uint2 u2[2]; u16 s[8]; } kv, vv;
      kv.u4 = *reinterpret_cast<const uint4*>(&Kin[base + (size_t)(k0 + r) * DIM + c8]);
      vv.u4 = *reinterpret_cast<const uint4*>(&Vin[base + (size_t)(k0 + r) * DIM + c8]);
      *reinterpret_cast<uint2*>(&Ks[r][c8])     = kv.u2[0];
      *reinterpret_cast<uint2*>(&Ks[r][c8 + 4]) = kv.u2[1];
#pragma unroll
      for (int e = 0; e < 8; ++e) Vt[c8 + e][r] = vv.s[e];
    }
    __syncthreads();

    bf16x8 kf[4];
#pragma unroll
    for (int kt = 0; kt < 4; ++kt) kf[kt] = ldfrag8(&Ks[kt * 16 + ln][g * 8]);

#pragma unroll
    for (int qt = 0; qt < 4; ++qt) {
      f32x4 s[4];
#pragma unroll
      for (int kt = 0; kt < 4; ++kt)
        s[kt] = __builtin_amdgcn_mfma_f32_16x16x32_bf16(kf[kt], qf[qt], zf, 0, 0, 0);
      // S^T C/D: row = kcol = kt*16+g*4+r, col = qrow = wq+qt*16+ln
      const int qrow = wq + qt * 16 + ln;
#pragma unroll
      for (int kt = 0; kt < 4; ++kt) {
        const float4 b4 = *reinterpret_cast<const float4*>(
            &simT2[((size_t)((k0 >> 2) + kt * 4 + g) * 512 + qrow) * 4]);
        s[kt][0] = fmaf(s[kt][0], scale, b4.x);
        s[kt][1] = fmaf(s[kt][1], scale, b4.y);
        s[kt][2] = fmaf(s[kt][2], scale, b4.z);
        s[kt][3] = fmaf(s[kt][3], scale, b4.w);
      }
      // online softmax for q-row = ln (replicated over 4 g-groups)
      float mx = s[0][0];
#pragma unroll
      for (int kt = 0; kt < 4; ++kt)
#pragma unroll
        for (int r = 0; r < 4; ++r) mx = fmaxf(mx, s[kt][r]);
      mx = fmaxf(mx, __shfl_xor(mx, 16));
      mx = fmaxf(mx, __shfl_xor(mx, 32));
      const float mnew = fmaxf(m[qt], mx);
      const float corr = __expf(m[qt] - mnew);
      m[qt] = mnew;
      float sum = 0.f;
      u16 pb[16];
#pragma unroll
      for (int kt = 0; kt < 4; ++kt)
#pragma unroll
        for (int r = 0; r < 4; ++r) {
          float p = __expf(s[kt][r] - mnew);
          sum += p;
          pb[kt * 4 + r] = f2b(p);
        }
      sum += __shfl_xor(sum, 16);
      sum += __shfl_xor(sum, 32);
      l[qt] = l[qt] * corr + sum;
#pragma unroll
      for (int kt = 0; kt < 4; ++kt)
#pragma unroll
        for (int r = 0; r < 4; ++r)
          Pws[w][qt * 16 + ln][kt * 16 + g * 4 + r] = pb[kt * 4 + r];
      // rescale O (o's q-row is g*4+r -> broadcast corr from lane g*4+r)
#pragma unroll
      for (int r = 0; r < 4; ++r) {
        const float cb = __shfl(corr, g * 4 + r);
        o[qt][0][r] *= cb;
        o[qt][1][r] *= cb;
      }
    }

    // PV: O[q][hd] += P[q][kv] * V[kv][hd]
    bf16x8 vf[2][2];
#pragma unroll
    for (int hf = 0; hf < 2; ++hf)
#pragma unroll
      for (int ks = 0; ks < 2; ++ks)
        vf[hf][ks] = ldfrag8(&Vt[hf * 16 + ln][ks * 32 + g * 8]);
#pragma unroll
    for (int qt = 0; qt < 4; ++qt)
#pragma unroll
      for (int ks = 0; ks < 2; ++ks) {
        bf16x8 pf = ldfrag8(&Pws[w][qt * 16 + ln][ks * 32 + g * 8]);
#pragma unroll
        for (int hf = 0; hf < 2; ++hf)
          o[qt][hf] = __builtin_amdgcn_mfma_f32_16x16x32_bf16(pf, vf[hf][ks], o[qt][hf], 0, 0, 0);
      }
    __syncthreads();
  }

#pragma unroll
  for (int qt = 0; qt < 4; ++qt) {
    const float invl = 1.0f / l[qt];
#pragma unroll
    for (int r = 0; r < 4; ++r) {
      const float il = __shfl(invl, g * 4 + r);
      const int qrow = wq + qt * 16 + g * 4 + r;
      O[base + (size_t)qrow * DIM + ln]      = f2b(o[qt][0][r] * il);
      O[base + (size_t)qrow * DIM + 16 + ln] = f2b(o[qt][1][r] * il);
    }
  }
}

extern "C" void kernel_launch(void* const* d_in, const int* in_sizes, int n_in,
                              void* d_out, int out_size, void* d_ws, size_t ws_size,
                              hipStream_t stream) {
  const float* x   = (const float*)d_in[0];
  const float* sim = (const float*)d_in[1];
  const float* Wq  = (const float*)d_in[2];
  const float* Wk  = (const float*)d_in[3];
  const float* Wv  = (const float*)d_in[4];
  const float* Wo  = (const float*)d_in[5];
  float* out = (float*)d_out;

  const int M = BTT * SEQ;               // 24576
  const size_t sz = (size_t)M * DIM;     // 6291456 elems
  const int WN = DIM * DIM;              // 65536

  u16* Qw   = (u16*)d_ws;
  u16* Kw   = Qw + sz;
  u16* Vw   = Kw + sz;
  u16* Xb   = Vw + sz;                   // bf16 x; becomes Aw after attn
  u16* Wqb  = Xb + sz;                   // transposed bf16 weights [N][K]
  u16* Wkb  = Wqb + WN;
  u16* Wvb  = Wkb + WN;
  u16* Wob  = Wvb + WN;
  float* simT2 = (float*)(Wob + WN);     // 1 MB packed bias

  cvt_kernel<<<(int)(sz / 4 / 256), 256, 0, stream>>>(x, Xb, (int)sz);
  dim3 wg(4, 4);
  wtcvt_kernel<<<wg, 256, 0, stream>>>(Wq, Wqb);
  wtcvt_kernel<<<wg, 256, 0, stream>>>(Wk, Wkb);
  wtcvt_kernel<<<wg, 256, 0, stream>>>(Wv, Wvb);
  wtcvt_kernel<<<wg, 256, 0, stream>>>(Wo, Wob);
  simpack_kernel<<<256, 256, 0, stream>>>(sim, simT2);

  dim3 gg(M / 128, DIM / 128);           // (192, 2)
  gemm_mfma<u16><<<gg, 256, 0, stream>>>(Xb, Wqb, Qw, M, DIM, DIM);
  gemm_mfma<u16><<<gg, 256, 0, stream>>>(Xb, Wkb, Kw, M, DIM, DIM);
  gemm_mfma<u16><<<gg, 256, 0, stream>>>(Xb, Wvb, Vw, M, DIM, DIM);

  u16* Aw = Xb;                          // reuse x buffer
  attn_mfma<<<dim3(2, NH, BTT), 256, 0, stream>>>(Qw, Kw, Vw, simT2, Aw);

  gemm_mfma<float><<<gg, 256, 0, stream>>>(Aw, Wob, out, M, DIM, DIM);
}

// Round 4
// 112.070 us; speedup vs baseline: 5.9977x; 1.6456x over previous
//
#include <hip/hip_runtime.h>
#include <hip/hip_bf16.h>

#define BTT 48      // B*T
#define SEQ 512     // spatial tokens
#define DIM 256     // model dim
#define NH  8       // heads
#define HD  32      // head dim
#define QKVD 768    // fused QKV row stride

typedef unsigned short u16;
typedef __attribute__((ext_vector_type(8))) short bf16x8;
typedef __attribute__((ext_vector_type(4))) float f32x4;

__device__ __forceinline__ u16 f2b(float f) {
  __hip_bfloat16 h = __float2bfloat16(f);
  union { __hip_bfloat16 h; u16 u; } c; c.h = h; return c.u;
}
__device__ __forceinline__ bf16x8 ldfrag8(const u16* p) {   // LDS, 8B-aligned
  union { uint2 u[2]; bf16x8 v; } f;
  f.u[0] = *reinterpret_cast<const uint2*>(p);
  f.u[1] = *reinterpret_cast<const uint2*>(p + 4);
  return f.v;
}
__device__ __forceinline__ bf16x8 ldfrag_g(const u16* p) {  // global, 16B-aligned
  union { uint4 u; bf16x8 v; } f;
  f.u = *reinterpret_cast<const uint4*>(p);
  return f.v;
}

// ---- fp32 -> bf16 flat conversion (x) ----
__global__ __launch_bounds__(256) void cvt_kernel(const float* __restrict__ src,
                                                  u16* __restrict__ dst, int n) {
  int i = (blockIdx.x * 256 + threadIdx.x) * 4;
  if (i >= n) return;
  float4 v = *reinterpret_cast<const float4*>(src + i);
  union { uint2 w; u16 u[4]; } o;
  o.u[0] = f2b(v.x); o.u[1] = f2b(v.y); o.u[2] = f2b(v.z); o.u[3] = f2b(v.w);
  *reinterpret_cast<uint2*>(dst + i) = o.w;
}

// ---- weight cvt + transpose: W[256][256] fp32 (k,n) -> Bt[256][256] bf16 (n,k) ----
__global__ __launch_bounds__(256) void wtcvt_kernel(const float* __restrict__ W,
                                                    u16* __restrict__ Bt) {
  __shared__ float Ls[64][65];
  const int t = threadIdx.x;
  const int kt = blockIdx.x * 64, nt = blockIdx.y * 64;
#pragma unroll
  for (int it = 0; it < 4; ++it) {
    int r = (t >> 4) + it * 16;
    int c = (t & 15) * 4;
    float4 v = *reinterpret_cast<const float4*>(&W[(size_t)(kt + r) * 256 + nt + c]);
    Ls[r][c] = v.x; Ls[r][c + 1] = v.y; Ls[r][c + 2] = v.z; Ls[r][c + 3] = v.w;
  }
  __syncthreads();
  const int n = t >> 2, kc = (t & 3) * 16;
  union { uint4 u[2]; u16 s[16]; } ob;
#pragma unroll
  for (int j = 0; j < 16; ++j) ob.s[j] = f2b(Ls[kc + j][n]);
  u16* dst = Bt + (size_t)(nt + n) * 256 + kt + kc;
  *reinterpret_cast<uint4*>(dst)     = ob.u[0];
  *reinterpret_cast<uint4*>(dst + 8) = ob.u[1];
}

// ---- sim[q][k] fp32 -> simT2[k>>2][q][k&3] fp32 ----
__global__ __launch_bounds__(256) void simpack_kernel(const float* __restrict__ sim,
                                                      float* __restrict__ simT2) {
  int gid = blockIdx.x * 256 + threadIdx.x;
  int q = gid & 511, k4 = gid >> 9;
  float4 v = *reinterpret_cast<const float4*>(&sim[(size_t)q * 512 + k4 * 4]);
  *reinterpret_cast<float4*>(&simT2[((size_t)k4 * 512 + q) * 4]) = v;
}

// ---- MFMA GEMM with register-prefetch double buffering ----
template <typename OUT>
__global__ __launch_bounds__(256) void gemm_mfma(const u16* __restrict__ A,
                                                 const u16* __restrict__ Bt,
                                                 OUT* __restrict__ C,
                                                 int M, int N, int K) {
  __shared__ u16 As[128][36];
  __shared__ u16 Bs[128][36];
  const int t = threadIdx.x, lane = t & 63, w = t >> 6;
  const int g = lane >> 4, ln = lane & 15;
  const int bm = blockIdx.x * 128, bn = blockIdx.y * 128;
  const int wr = (w & 1) * 64, wc = (w >> 1) * 64;
  const f32x4 zf = {0.f, 0.f, 0.f, 0.f};
  f32x4 acc[4][4];
#pragma unroll
  for (int i = 0; i < 4; ++i)
#pragma unroll
    for (int j = 0; j < 4; ++j) acc[i][j] = zf;

  const int r0 = t >> 2, c8 = (t & 3) * 8;
  uint4 apre[2], bpre[2];
#pragma unroll
  for (int p = 0; p < 2; ++p) {
    apre[p] = *reinterpret_cast<const uint4*>(&A [(size_t)(bm + r0 + p * 64) * K + c8]);
    bpre[p] = *reinterpret_cast<const uint4*>(&Bt[(size_t)(bn + r0 + p * 64) * K + c8]);
  }

  for (int k0 = 0; k0 < K; k0 += 32) {
#pragma unroll
    for (int p = 0; p < 2; ++p) {
      const int r = r0 + p * 64;
      union { uint4 u4; uint2 u2[2]; } av, bv;
      av.u4 = apre[p]; bv.u4 = bpre[p];
      *reinterpret_cast<uint2*>(&As[r][c8])     = av.u2[0];
      *reinterpret_cast<uint2*>(&As[r][c8 + 4]) = av.u2[1];
      *reinterpret_cast<uint2*>(&Bs[r][c8])     = bv.u2[0];
      *reinterpret_cast<uint2*>(&Bs[r][c8 + 4]) = bv.u2[1];
    }
    if (k0 + 32 < K) {
#pragma unroll
      for (int p = 0; p < 2; ++p) {
        apre[p] = *reinterpret_cast<const uint4*>(&A [(size_t)(bm + r0 + p * 64) * K + k0 + 32 + c8]);
        bpre[p] = *reinterpret_cast<const uint4*>(&Bt[(size_t)(bn + r0 + p * 64) * K + k0 + 32 + c8]);
      }
    }
    __syncthreads();
    bf16x8 af[4], bfr[4];
#pragma unroll
    for (int i = 0; i < 4; ++i) af[i]  = ldfrag8(&As[wr + i * 16 + ln][g * 8]);
#pragma unroll
    for (int j = 0; j < 4; ++j) bfr[j] = ldfrag8(&Bs[wc + j * 16 + ln][g * 8]);
#pragma unroll
    for (int i = 0; i < 4; ++i)
#pragma unroll
      for (int j = 0; j < 4; ++j)
        acc[i][j] = __builtin_amdgcn_mfma_f32_16x16x32_bf16(af[i], bfr[j], acc[i][j], 0, 0, 0);
    __syncthreads();
  }
#pragma unroll
  for (int i = 0; i < 4; ++i)
#pragma unroll
    for (int j = 0; j < 4; ++j)
#pragma unroll
      for (int r = 0; r < 4; ++r) {
        const int row = bm + wr + i * 16 + g * 4 + r;
        const int col = bn + wc + j * 16 + ln;
        if constexpr (sizeof(OUT) == 2)
          ((u16*)C)[(size_t)row * N + col] = f2b(acc[i][j][r]);
        else
          ((float*)C)[(size_t)row * N + col] = acc[i][j][r];
      }
}

// ---- MFMA flash attention, swapped QK^T, NO online max (raw-exp softmax) ----
// 4 waves x 64 q-rows; KV tiles of 64, double-buffered staging, 1 barrier/iter.
__global__ __launch_bounds__(256) void attn_mfma2(const u16* __restrict__ QKV,
                                                  const float* __restrict__ simT2,
                                                  u16* __restrict__ O) {
  __shared__ u16 Ks[2][64][36];     // [buf][kv][hd]
  __shared__ u16 Vt[2][32][68];     // [buf][hd][kv]
  __shared__ u16 Pws[4][64][68];    // per-wave P [qrow][kv]

  const int t = threadIdx.x;
  const int lane = t & 63, w = t >> 6;
  const int g = lane >> 4, ln = lane & 15;
  const int qb = blockIdx.x * 256;
  const int h = blockIdx.y, bt = blockIdx.z;
  const size_t base = (size_t)bt * SEQ * QKVD + (size_t)h * HD;
  const u16* Qp = QKV + base;
  const u16* Kp = QKV + base + 256;
  const u16* Vp = QKV + base + 512;
  const size_t baseo = (size_t)bt * SEQ * DIM + (size_t)h * HD;
  const int wq = qb + w * 64;
  const float scale = 0.17677669529663687f;  // 1/sqrt(32)
  const f32x4 zf = {0.f, 0.f, 0.f, 0.f};

  bf16x8 qf[4];
#pragma unroll
  for (int qt = 0; qt < 4; ++qt)
    qf[qt] = ldfrag_g(&Qp[(size_t)(wq + qt * 16 + ln) * QKVD + g * 8]);

  f32x4 o[4][2];
  float lacc[4];
#pragma unroll
  for (int qt = 0; qt < 4; ++qt) { o[qt][0] = zf; o[qt][1] = zf; lacc[qt] = 0.f; }

  const int sr = t >> 2, sc8 = (t & 3) * 8;
  uint4 kreg = *reinterpret_cast<const uint4*>(&Kp[(size_t)sr * QKVD + sc8]);
  uint4 vreg = *reinterpret_cast<const uint4*>(&Vp[(size_t)sr * QKVD + sc8]);

  for (int it = 0; it < 8; ++it) {
    const int buf = it & 1;
    {   // write staged regs to LDS
      union { uint4 u4; uint2 u2[2]; u16 s[8]; } kv, vv;
      kv.u4 = kreg; vv.u4 = vreg;
      *reinterpret_cast<uint2*>(&Ks[buf][sr][sc8])     = kv.u2[0];
      *reinterpret_cast<uint2*>(&Ks[buf][sr][sc8 + 4]) = kv.u2[1];
#pragma unroll
      for (int e = 0; e < 8; ++e) Vt[buf][sc8 + e][sr] = vv.s[e];
    }
    if (it < 7) {   // prefetch next tile (latency hides under compute)
      const size_t off = (size_t)(it + 1) * 64 * QKVD + (size_t)sr * QKVD + sc8;
      kreg = *reinterpret_cast<const uint4*>(&Kp[off]);
      vreg = *reinterpret_cast<const uint4*>(&Vp[off]);
    }
    __syncthreads();

    const int k0 = it * 64;
    bf16x8 kf[4];
#pragma unroll
    for (int kt = 0; kt < 4; ++kt) kf[kt] = ldfrag8(&Ks[buf][kt * 16 + ln][g * 8]);
    bf16x8 vf[2][2];
#pragma unroll
    for (int hf = 0; hf < 2; ++hf)
#pragma unroll
      for (int ks = 0; ks < 2; ++ks)
        vf[hf][ks] = ldfrag8(&Vt[buf][hf * 16 + ln][ks * 32 + g * 8]);

#pragma unroll
    for (int qt = 0; qt < 4; ++qt) {
      f32x4 s[4];
      __builtin_amdgcn_s_setprio(1);
#pragma unroll
      for (int kt = 0; kt < 4; ++kt)
        s[kt] = __builtin_amdgcn_mfma_f32_16x16x32_bf16(kf[kt], qf[qt], zf, 0, 0, 0);
      __builtin_amdgcn_s_setprio(0);
      const int qrow = wq + qt * 16 + ln;
      float lsum = 0.f;
#pragma unroll
      for (int kt = 0; kt < 4; ++kt) {
        const float4 b4 = *reinterpret_cast<const float4*>(
            &simT2[((size_t)((k0 >> 2) + kt * 4 + g) * 512 + qrow) * 4]);
        const float e0 = __expf(fmaf(s[kt][0], scale, b4.x));
        const float e1 = __expf(fmaf(s[kt][1], scale, b4.y));
        const float e2 = __expf(fmaf(s[kt][2], scale, b4.z));
        const float e3 = __expf(fmaf(s[kt][3], scale, b4.w));
        lsum += (e0 + e1) + (e2 + e3);
        union { uint2 w2; u16 us[4]; } pw;
        pw.us[0] = f2b(e0); pw.us[1] = f2b(e1); pw.us[2] = f2b(e2); pw.us[3] = f2b(e3);
        *reinterpret_cast<uint2*>(&Pws[w][qt * 16 + ln][kt * 16 + g * 4]) = pw.w2;
      }
      lacc[qt] += lsum;
      // PV for this qt (per-wave LDS, no barrier needed)
      __builtin_amdgcn_s_setprio(1);
#pragma unroll
      for (int ks = 0; ks < 2; ++ks) {
        bf16x8 pf = ldfrag8(&Pws[w][qt * 16 + ln][ks * 32 + g * 8]);
#pragma unroll
        for (int hf = 0; hf < 2; ++hf)
          o[qt][hf] = __builtin_amdgcn_mfma_f32_16x16x32_bf16(pf, vf[hf][ks], o[qt][hf], 0, 0, 0);
      }
      __builtin_amdgcn_s_setprio(0);
    }
    // no second barrier: next iter writes the other staging buffer
  }

#pragma unroll
  for (int qt = 0; qt < 4; ++qt) {
    float l = lacc[qt];
    l += __shfl_xor(l, 16);
    l += __shfl_xor(l, 32);
    const float invl = 1.0f / l;
#pragma unroll
    for (int r = 0; r < 4; ++r) {
      const float il = __shfl(invl, g * 4 + r);
      const int qrow = wq + qt * 16 + g * 4 + r;
      O[baseo + (size_t)qrow * DIM + ln]      = f2b(o[qt][0][r] * il);
      O[baseo + (size_t)qrow * DIM + 16 + ln] = f2b(o[qt][1][r] * il);
    }
  }
}

extern "C" void kernel_launch(void* const* d_in, const int* in_sizes, int n_in,
                              void* d_out, int out_size, void* d_ws, size_t ws_size,
                              hipStream_t stream) {
  const float* x   = (const float*)d_in[0];
  const float* sim = (const float*)d_in[1];
  const float* Wq  = (const float*)d_in[2];
  const float* Wk  = (const float*)d_in[3];
  const float* Wv  = (const float*)d_in[4];
  const float* Wo  = (const float*)d_in[5];
  float* out = (float*)d_out;

  const int M = BTT * SEQ;               // 24576
  const size_t sz = (size_t)M * DIM;     // 6291456
  const int WN = DIM * DIM;              // 65536

  u16* QKVw  = (u16*)d_ws;               // [M][768] bf16
  u16* Xb    = QKVw + (size_t)M * QKVD;  // [M][256] bf16 x; becomes Aw
  u16* Wqkvb = Xb + sz;                  // [768][256] bf16 (n,k): Q|K|V
  u16* Wob   = Wqkvb + (size_t)3 * WN;   // [256][256] bf16 (n,k)
  float* simT2 = (float*)(Wob + WN);     // 1 MB packed bias

  cvt_kernel<<<(int)(sz / 4 / 256), 256, 0, stream>>>(x, Xb, (int)sz);
  dim3 wg(4, 4);
  wtcvt_kernel<<<wg, 256, 0, stream>>>(Wq, Wqkvb);
  wtcvt_kernel<<<wg, 256, 0, stream>>>(Wk, Wqkvb + WN);
  wtcvt_kernel<<<wg, 256, 0, stream>>>(Wv, Wqkvb + 2 * WN);
  wtcvt_kernel<<<wg, 256, 0, stream>>>(Wo, Wob);
  simpack_kernel<<<256, 256, 0, stream>>>(sim, simT2);

  // fused QKV projection: [M,256] x [256,768] -> [M,768]
  gemm_mfma<u16><<<dim3(M / 128, QKVD / 128), 256, 0, stream>>>(Xb, Wqkvb, QKVw, M, QKVD, DIM);

  u16* Aw = Xb;                          // x dead; reuse as attention output
  attn_mfma2<<<dim3(2, NH, BTT), 256, 0, stream>>>(QKVw, simT2, Aw);

  gemm_mfma<float><<<dim3(M / 128, DIM / 128), 256, 0, stream>>>(Aw, Wob, out, M, DIM, DIM);
}